// Round 5
// baseline (260.966 us; speedup 1.0000x reference)
//
#include <hip/hip_runtime.h>

typedef __bf16 bf16x8 __attribute__((ext_vector_type(8)));
typedef float  f32x4  __attribute__((ext_vector_type(4)));
typedef unsigned short u16x8 __attribute__((ext_vector_type(8)));
typedef unsigned short u16x4 __attribute__((ext_vector_type(4)));

// Problem constants
constexpr int BB    = 16;
constexpr int TT    = 12;
constexpr int NN    = 307;
constexpr int TN    = TT * NN;        // 3684
constexpr int ROWSX = BB * TT * NN;   // 58944
constexpr int ROWSH = BB * NN;        // 4912
constexpr int SST1  = 3712;           // sag row stride (464 x b128 chunks)
constexpr int SSTR  = 3840;           // xnT row stride
constexpr int HPS   = ROWSH * 64;     // hp slab stride (314368 floats)
constexpr int KQ    = 928;            // pv K-split chunk (3712/4)
constexpr int WBS   = 152;            // score LDS stride: 76 dw = 12 mod 32 -> 2-way max
constexpr float SCALE = 0.125f;

__device__ __forceinline__ float wred_sum(float v) {
#pragma unroll
    for (int m = 32; m > 0; m >>= 1) v += __shfl_xor(v, m, 64);
    return v;
}

// ---------------------------------------------------------------------------
// Fold q/k projections: dg = q.k = qt.x_ + c
// ---------------------------------------------------------------------------
__global__ void fold_k(const float* __restrict__ qw, const float* __restrict__ qb,
                       const float* __restrict__ kw, const float* __restrict__ kb,
                       float* __restrict__ M, float* __restrict__ b2,
                       float* __restrict__ vv, float* __restrict__ cc) {
    int e = blockIdx.x, d = threadIdx.x;
    float acc = 0.f;
    for (int dp = 0; dp < 64; ++dp) acc += qw[dp * 64 + e] * kw[dp * 64 + d];
    M[e * 64 + d] = acc;
    float vp = wred_sum(qw[d * 64 + e] * kb[d]);
    if (d == 0) vv[e] = vp;
    if (e == 0) {
        float b = 0.f;
        for (int dp = 0; dp < 64; ++dp) b += qb[dp] * kw[dp * 64 + d];
        b2[d] = b;
        float cp = wred_sum(qb[d] * kb[d]);
        if (d == 0) *cc = cp;
    }
}

// ---------------------------------------------------------------------------
// fc1w/fc2w fp32 -> bf16
// ---------------------------------------------------------------------------
__global__ void wconv_k(const float* __restrict__ fc1w, const float* __restrict__ fc2w,
                        __bf16* __restrict__ fc1b16, __bf16* __restrict__ fc2b16) {
    int i = blockIdx.x * 256 + threadIdx.x;
    if (i < 16384) fc1b16[i] = (__bf16)fc1w[i];
    else fc2b16[i - 16384] = (__bf16)fc2w[i - 16384];
}

// ---------------------------------------------------------------------------
// LayerNorm -> xnb (bf16) + y32 (fp32, t==11 slab). 1 row/wave.
// ---------------------------------------------------------------------------
__global__ __launch_bounds__(256) void ln_k(const float* __restrict__ x,
                                            const float* __restrict__ g,
                                            const float* __restrict__ b,
                                            __bf16* __restrict__ xnb,
                                            float* __restrict__ y32) {
    int w = threadIdx.x >> 6, l = threadIdx.x & 63;
    int r = blockIdx.x * 4 + w;
    if (r >= ROWSX) return;
    float val = x[r * 64 + l];
    float mu  = wred_sum(val) * (1.f / 64.f);
    float dv  = val - mu;
    float var = wred_sum(dv * dv) * (1.f / 64.f);
    float xv  = dv * rsqrtf(var + 1e-5f) * g[l] + b[l];
    xnb[(size_t)r * 64 + l] = (__bf16)xv;
    int t = (r / NN) % TT;
    if (t == TT - 1) {
        int bbv = r / (NN * TT), n = r % NN;
        y32[(bbv * NN + n) * 64 + l] = xv;
    }
}

// ---------------------------------------------------------------------------
// Transpose xnb[b,j,d] -> xnT[b,d,j] (stride SSTR; j>=TN zero within tiles)
// ---------------------------------------------------------------------------
__global__ __launch_bounds__(256) void t_k(const __bf16* __restrict__ xnb,
                                           __bf16* __restrict__ xnT) {
    __shared__ unsigned short tile[64][65];
    int bb = blockIdx.y, j0 = blockIdx.x * 64, t = threadIdx.x;
    const unsigned short* src = (const unsigned short*)xnb;
    unsigned short* dst = (unsigned short*)xnT;
#pragma unroll
    for (int i = 0; i < 16; ++i) {
        int f = t + 256 * i, jr = f >> 6, dc = f & 63;
        int j = j0 + jr;
        tile[jr][dc] = (j < TN) ? src[((size_t)bb * TN + j) * 64 + dc] : (unsigned short)0;
    }
    __syncthreads();
#pragma unroll
    for (int i = 0; i < 16; ++i) {
        int f = t + 256 * i, d = f >> 6, jj = f & 63;
        dst[((size_t)bb * 64 + d) * SSTR + j0 + jj] = tile[jj][d];
    }
}

// ---------------------------------------------------------------------------
// qt[row] = y_ @ M + b2 (bf16);  cq[row] = y_.v + cc
// ---------------------------------------------------------------------------
__global__ __launch_bounds__(256) void qt_k(const float* __restrict__ y32,
                                            const float* __restrict__ M,
                                            const float* __restrict__ b2,
                                            const float* __restrict__ vv,
                                            const float* __restrict__ ccp,
                                            __bf16* __restrict__ qtb,
                                            float* __restrict__ cq) {
    int w = threadIdx.x >> 6, l = threadIdx.x & 63;
    int rr = blockIdx.x * 4 + w;
    if (rr >= ROWSH) return;
    float y = y32[rr * 64 + l];
    float acc = b2[l];
#pragma unroll
    for (int e = 0; e < 64; ++e) acc += __shfl(y, e, 64) * M[e * 64 + l];
    qtb[(size_t)rr * 64 + l] = (__bf16)acc;
    float cp = wred_sum(y * vv[l]);
    if (l == 0) cq[rr] = cp + *ccp;
}

// ---------------------------------------------------------------------------
// Score GEMM via MFMA. Register-prefetch stg float4 + cq before MFMA; LDS
// stride 152 (2-way max on scatter); coalesced b128 stores.
// ---------------------------------------------------------------------------
__global__ __launch_bounds__(256, 4) void score_k(const __bf16* __restrict__ qtb,
                                                  const float* __restrict__ cq,
                                                  const __bf16* __restrict__ xnb,
                                                  const float* __restrict__ stg,
                                                  __bf16* __restrict__ sag) {
    __shared__ unsigned short wb[64 * WBS];   // 19.5 KB  [n(64)][j(128+pad)]
    int bb = blockIdx.z, n0 = blockIdx.y * 64, j0 = blockIdx.x * 128;
    int t = threadIdx.x;
    int w = t >> 6, lane = t & 63;
    int m16 = lane & 15, q4 = lane >> 4;

    // ---- prefetch stg tiles (8 x float4) + cq (4) into registers ----
    const float* stgb = stg + (size_t)bb * NN * TN;
    float4 sv[4][2];
    float cn[4];
#pragma unroll
    for (int nt = 0; nt < 4; ++nt) {
        int n = n0 + nt * 16 + m16;
        const float* srow = stgb + (size_t)min(n, NN - 1) * TN;
#pragma unroll
        for (int jj = 0; jj < 2; ++jj) {
            int jb = j0 + (w * 2 + jj) * 16 + q4 * 4;   // 4-aligned; TN is 4-aligned
            float4 s4 = {0.f, 0.f, 0.f, 0.f};
            if (jb < TN) s4 = *(const float4*)(srow + jb);
            sv[nt][jj] = s4;
        }
        cn[nt] = (n < NN) ? cq[bb * NN + n] : 0.f;
    }

    // ---- A fragments: xnb rows j (2 jt tiles per wave) ----
    bf16x8 a[2][2];
#pragma unroll
    for (int jj = 0; jj < 2; ++jj) {
        const bf16x8* ap = (const bf16x8*)(xnb + ((size_t)bb * TN + j0 + (w * 2 + jj) * 16 + m16) * 64);
        a[jj][0] = ap[q4];
        a[jj][1] = ap[q4 + 4];
    }

    // ---- MFMA: C[j_local][n_local], 2 jt x 4 nt tiles per wave ----
    f32x4 acc[2][4];
#pragma unroll
    for (int nt = 0; nt < 4; ++nt) {
        const bf16x8* bp = (const bf16x8*)(qtb + ((size_t)bb * NN + n0 + nt * 16 + m16) * 64);
        bf16x8 b0 = bp[q4], b1 = bp[q4 + 4];
#pragma unroll
        for (int jj = 0; jj < 2; ++jj) {
            f32x4 c = {0.f, 0.f, 0.f, 0.f};
            c = __builtin_amdgcn_mfma_f32_16x16x32_bf16(a[jj][0], b0, c, 0, 0, 0);
            c = __builtin_amdgcn_mfma_f32_16x16x32_bf16(a[jj][1], b1, c, 0, 0, 0);
            acc[jj][nt] = c;
        }
    }

    // ---- epilogue: sigmoid(dg)*stg*scale from registers only ----
#pragma unroll
    for (int nt = 0; nt < 4; ++nt) {
#pragma unroll
        for (int jj = 0; jj < 2; ++jj) {
            int jb = j0 + (w * 2 + jj) * 16 + q4 * 4;
            float svv[4] = {sv[nt][jj].x, sv[nt][jj].y, sv[nt][jj].z, sv[nt][jj].w};
            u16x4 hw;
#pragma unroll
            for (int r = 0; r < 4; ++r) {
                float dg = (acc[jj][nt][r] + cn[nt]) * SCALE;
                float s  = 1.f / (1.f + __expf(-dg));
                float wv = (jb + r < TN) ? s * svv[r] * SCALE : 0.f;
                __bf16 wb16 = (__bf16)wv;
                hw[r] = *(unsigned short*)&wb16;
            }
            *(u16x4*)&wb[(nt * 16 + m16) * WBS + (w * 2 + jj) * 16 + q4 * 4] = hw;
        }
    }
    __syncthreads();

    // ---- coalesced b128 stores ----
#pragma unroll
    for (int i = 0; i < 4; ++i) {
        int chunk = t + i * 256;          // 0..1023
        int row = chunk >> 4, c8 = (chunk & 15) * 8;
        int n = n0 + row;
        if (n < NN) {
            u16x8 v = *(const u16x8*)&wb[row * WBS + c8];
            *(u16x8*)((unsigned short*)sag + (size_t)(bb * NN + n) * SST1 + j0 + c8) = v;
        }
    }
}

// ---------------------------------------------------------------------------
// Stats-only softmax pass (v3): reads sag once, emits per-row {vmax, bit
// threshold, sign-encoded sum}. NO sag rewrite (was a 36.5MB write + full
// store pass); pv_k applies exp inline. rsum<0 encodes the degenerate
// uniform row (|rsum|=TN, weights 1 on valid cols).
// ---------------------------------------------------------------------------
__global__ __launch_bounds__(256) void smax_k(const __bf16* __restrict__ sagB,
                                              const int* __restrict__ topk_p,
                                              float* __restrict__ rsum,
                                              float* __restrict__ vmaxf,
                                              unsigned* __restrict__ thrv) {
    int t = threadIdx.x;
    int wid = t >> 6, lane = t & 63;
    int row = blockIdx.x * 4 + wid;
    if (row >= ROWSH) return;

    int topkv = *topk_p;
    bool selAll = (topkv <= 0);
    int kk = 0;
    if (!selAll) {
        kk = (topkv < 5) ? topkv * NN : topkv;
        if (kk > TN) kk = TN;
    }

    const u16x8* src = (const u16x8*)((const unsigned short*)sagB + (size_t)row * SST1);
    u16x8 va[8];
#pragma unroll
    for (int ci = 0; ci < 8; ++ci) {
        int c = lane + (ci << 6);
        u16x8 v = {0, 0, 0, 0, 0, 0, 0, 0};
        if (c < 464) v = src[c];
        va[ci] = v;
    }
    // row max (values >= 0; bf16 bit order = value order; pads 0)
    int vmb = 0;
#pragma unroll
    for (int ci = 0; ci < 8; ++ci)
#pragma unroll
        for (int e = 0; e < 8; ++e) vmb = max(vmb, (int)va[ci][e]);
#pragma unroll
    for (int m = 32; m > 0; m >>= 1) vmb = max(vmb, __shfl_xor(vmb, m, 64));
    float vmax = __uint_as_float(((unsigned)vmb) << 16);

    // exact kk-th largest: smallest T with cnt(>T) < kk (ballot+popcount)
    unsigned thrb = 0;
    if (!selAll) {
        unsigned lo = 0, hi = (unsigned)vmb;
        while (lo < hi) {
            unsigned mid = (lo + hi) >> 1;
            int cnt = 0;
#pragma unroll
            for (int ci = 0; ci < 8; ++ci)
#pragma unroll
                for (int e = 0; e < 8; ++e)
                    cnt += (int)__popcll(__ballot((unsigned)va[ci][e] > mid));
            if (cnt < kk) hi = mid; else lo = mid + 1;
        }
        thrb = lo;
    }

    // sum of exp over selected (no store-back)
    float local = 0.f;
#pragma unroll
    for (int ci = 0; ci < 8; ++ci) {
        int c = lane + (ci << 6);
        int nvv = (c < 460) ? 8 : ((c == 460) ? 4 : 0);
#pragma unroll
        for (int e = 0; e < 8; ++e) {
            unsigned u = va[ci][e];
            bool sel = selAll ? (e < nvv) : (u > thrb);
            local += sel ? __expf(__uint_as_float(u << 16) - vmax) : 0.f;
        }
    }
    local = wred_sum(local);
    if (lane == 0) {
        bool uni = !(local > 0.f);
        rsum[row]  = uni ? -(float)TN : local;
        vmaxf[row] = vmax;
        thrv[row]  = thrb;
    }
}

// ---------------------------------------------------------------------------
// PV GEMM with inline softmax (v3): loads raw sag scores, applies topk
// select + exp(v - vmax) per element while building the A fragment (same
// bf16 rounding point as before), divides by |rsum| in the epilogue.
// K-split 4 across blocks; ffn_k sums the slabs.
// ---------------------------------------------------------------------------
__global__ __launch_bounds__(256) void pv_k(const __bf16* __restrict__ sagB,
                                            const __bf16* __restrict__ xnT,
                                            const float* __restrict__ y32,
                                            const float* __restrict__ rsum,
                                            const float* __restrict__ vmaxf,
                                            const unsigned* __restrict__ thrv,
                                            const int* __restrict__ topk_p,
                                            float* __restrict__ hp) {
    int bb = blockIdx.z, kq = blockIdx.y, n0 = blockIdx.x * 16;
    int wid = threadIdx.x >> 6, lane = threadIdx.x & 63;
    int m16 = lane & 15, q4 = lane >> 4;

    bool selAll = (*topk_p <= 0);
    int arow = min(n0 + m16, NN - 1);   // clamp: garbage rows masked at store
    int ridx = bb * NN + arow;
    float rsA   = rsum[ridx];
    bool  uniA  = rsA < 0.f;
    float vmaxA = vmaxf[ridx];
    unsigned thrA = thrv[ridx];

    const __bf16* ab  = sagB + (size_t)ridx * SST1 + kq * KQ + q4 * 8;
    const __bf16* bbp = xnT + ((size_t)bb * 64 + wid * 16 + m16) * SSTR + kq * KQ + q4 * 8;

    f32x4 acc0 = {0.f, 0.f, 0.f, 0.f}, acc1 = {0.f, 0.f, 0.f, 0.f};
#pragma unroll 4
    for (int ks = 0; ks < 29; ++ks) {               // 29 * K32 = 928
        u16x8 ub = *(const u16x8*)(ab + ks * 32);
        bf16x8 b = *(const bf16x8*)(bbp + ks * 32);
        int jb = kq * KQ + ks * 32 + q4 * 8;
        bf16x8 aw;
#pragma unroll
        for (int e = 0; e < 8; ++e) {
            unsigned u = ub[e];
            bool valid = (jb + e) < TN;
            bool sel = selAll ? valid : (u > thrA);
            float ev = sel ? __expf(__uint_as_float(u << 16) - vmaxA) : 0.f;
            ev = uniA ? (valid ? 1.f : 0.f) : ev;
            aw[e] = (__bf16)ev;
        }
        if (ks & 1) acc1 = __builtin_amdgcn_mfma_f32_16x16x32_bf16(aw, b, acc1, 0, 0, 0);
        else        acc0 = __builtin_amdgcn_mfma_f32_16x16x32_bf16(aw, b, acc0, 0, 0, 0);
    }
    // C layout: row = q4*4+r (A-row = n), col = m16 (B-row = d within tile)
#pragma unroll
    for (int r = 0; r < 4; ++r) {
        int n = n0 + q4 * 4 + r;
        if (n < NN) {
            size_t o = (size_t)(bb * NN + n) * 64 + wid * 16 + m16;
            float inv = 1.f / fabsf(rsum[bb * NN + n]);
            float v = (acc0[r] + acc1[r]) * inv;
            if (kq == 0) v += y32[o];
            hp[(size_t)kq * HPS + o] = v;
        }
    }
}

// ---------------------------------------------------------------------------
// FFN via MFMA bf16: h = sum(hp[0..3]) -> LN -> @fc1^T+relu -> @fc2^T + h + b.
// ---------------------------------------------------------------------------
__global__ __launch_bounds__(256) void ffn_k(const float* __restrict__ hp,
                                             const float* __restrict__ g,
                                             const float* __restrict__ bln,
                                             const __bf16* __restrict__ fc1b16,
                                             const float* __restrict__ fc1b,
                                             const __bf16* __restrict__ fc2b16,
                                             const float* __restrict__ fc2b,
                                             float* __restrict__ out) {
    __shared__ __bf16 zb[16 * 68];
    __shared__ __bf16 ab[16 * 264];
    int t = threadIdx.x, r0 = blockIdx.x * 16;
    int wid = t >> 6, lane = t & 63;
    int m16 = lane & 15, q4 = lane >> 4;

#pragma unroll
    for (int q = 0; q < 4; ++q) {
        int rl = wid * 4 + q;
        size_t i = (size_t)(r0 + rl) * 64 + lane;
        float val = hp[i] + hp[HPS + i] + hp[2 * HPS + i] + hp[3 * HPS + i];
        float mu  = wred_sum(val) * (1.f / 64.f);
        float dv  = val - mu;
        float var = wred_sum(dv * dv) * (1.f / 64.f);
        zb[rl * 68 + lane] = (__bf16)(dv * rsqrtf(var + 1e-5f) * g[lane] + bln[lane]);
    }
    __syncthreads();

    bf16x8 a0 = *(const bf16x8*)&zb[m16 * 68 + q4 * 8];
    bf16x8 a1 = *(const bf16x8*)&zb[m16 * 68 + 32 + q4 * 8];
#pragma unroll
    for (int jt2 = 0; jt2 < 4; ++jt2) {
        int j0t = (wid * 4 + jt2) * 16;
        const __bf16* bp = fc1b16 + (size_t)(j0t + m16) * 64 + q4 * 8;
        f32x4 c = {0.f, 0.f, 0.f, 0.f};
        c = __builtin_amdgcn_mfma_f32_16x16x32_bf16(a0, *(const bf16x8*)bp, c, 0, 0, 0);
        c = __builtin_amdgcn_mfma_f32_16x16x32_bf16(a1, *(const bf16x8*)(bp + 32), c, 0, 0, 0);
        int j = j0t + m16;
        float bias = fc1b[j];
#pragma unroll
        for (int r = 0; r < 4; ++r)
            ab[(q4 * 4 + r) * 264 + j] = (__bf16)fmaxf(c[r] + bias, 0.f);
    }
    __syncthreads();

    f32x4 c2a = {0.f, 0.f, 0.f, 0.f}, c2b = {0.f, 0.f, 0.f, 0.f};
    const __bf16* b2p = fc2b16 + (size_t)(wid * 16 + m16) * 256 + q4 * 8;
#pragma unroll
    for (int k8 = 0; k8 < 8; k8 += 2) {
        bf16x8 aa0 = *(const bf16x8*)&ab[m16 * 264 + k8 * 32 + q4 * 8];
        bf16x8 aa1 = *(const bf16x8*)&ab[m16 * 264 + (k8 + 1) * 32 + q4 * 8];
        c2a = __builtin_amdgcn_mfma_f32_16x16x32_bf16(aa0, *(const bf16x8*)(b2p + k8 * 32), c2a, 0, 0, 0);
        c2b = __builtin_amdgcn_mfma_f32_16x16x32_bf16(aa1, *(const bf16x8*)(b2p + (k8 + 1) * 32), c2b, 0, 0, 0);
    }
    int d = wid * 16 + m16;
    float bias2 = fc2b[d];
#pragma unroll
    for (int r = 0; r < 4; ++r) {
        size_t row = (size_t)(r0 + q4 * 4 + r);
        size_t o = row * 64 + d;
        float hsum = hp[o] + hp[HPS + o] + hp[2 * HPS + o] + hp[3 * HPS + o];
        out[o] = hsum + c2a[r] + c2b[r] + bias2;
    }
}

extern "C" void kernel_launch(void* const* d_in, const int* in_sizes, int n_in,
                              void* d_out, int out_size, void* d_ws, size_t ws_size,
                              hipStream_t stream) {
    const float* x    = (const float*)d_in[0];
    const float* stg  = (const float*)d_in[1];
    const int*   topk = (const int*)d_in[2];
    const float* qw   = (const float*)d_in[3];
    const float* qb   = (const float*)d_in[4];
    const float* kw   = (const float*)d_in[5];
    const float* kb   = (const float*)d_in[6];
    const float* lng  = (const float*)d_in[7];
    const float* lnb  = (const float*)d_in[8];
    const float* flng = (const float*)d_in[9];
    const float* flnb = (const float*)d_in[10];
    const float* fc1w = (const float*)d_in[11];
    const float* fc1b = (const float*)d_in[12];
    const float* fc2w = (const float*)d_in[13];
    const float* fc2b = (const float*)d_in[14];
    float* out = (float*)d_out;

    float* ws = (float*)d_ws;
    __bf16* xnb = (__bf16*)ws;                 // ROWSX*64 bf16 = 1,886,208 f
    float* p1   = ws + 1886208;
    __bf16* xnT = (__bf16*)p1;                 // 16*64*3840 bf16 = 1,966,080 f
    float* p2   = p1 + 1966080;
    __bf16* qtb = (__bf16*)p2;                 // 4928*64 bf16 = 157,696 f
    float* y32  = p2 + 157696;                 // 314,368 f
    float* cq   = y32 + 314368;                // 4,928 f
    float* M    = cq + 4928;                   // 4,096
    float* b2   = M + 4096;                    // 64
    float* vv   = b2 + 64;                     // 64
    float* cc   = vv + 64;                     // 16
    __bf16* fc1b16 = (__bf16*)(cc + 16);       // 8,192 f
    __bf16* fc2b16 = (__bf16*)((float*)fc1b16 + 8192);  // 8,192 f
    __bf16* sag = (__bf16*)((float*)fc2b16 + 8192);     // ROWSH*3712 bf16 = 9,116,672 f
    float* hp   = (float*)sag + 9116672;       // 4*314,368 f (K-split partials)
    float* rsum = hp + 4 * HPS;                // 4,928 f
    float* vmaxf = rsum + 4928;                // 4,928 f
    unsigned* thrv = (unsigned*)(vmaxf + 4928);// 4,928 u32

    fold_k<<<64, 64, 0, stream>>>(qw, qb, kw, kb, M, b2, vv, cc);
    wconv_k<<<128, 256, 0, stream>>>(fc1w, fc2w, fc1b16, fc2b16);
    ln_k<<<(ROWSX + 3) / 4, 256, 0, stream>>>(x, lng, lnb, xnb, y32);
    t_k<<<dim3((TN + 63) / 64, BB), 256, 0, stream>>>(xnb, xnT);
    qt_k<<<(ROWSH + 3) / 4, 256, 0, stream>>>(y32, M, b2, vv, cc, qtb, cq);
    score_k<<<dim3((TN + 127) / 128, (NN + 63) / 64, BB), 256, 0, stream>>>(qtb, cq, xnb, stg, sag);
    smax_k<<<(ROWSH + 3) / 4, 256, 0, stream>>>(sag, topk, rsum, vmaxf, thrv);
    pv_k<<<dim3((NN + 15) / 16, 4, BB), 256, 0, stream>>>(sag, xnT, y32, rsum, vmaxf, thrv, topk, hp);
    ffn_k<<<ROWSH / 16, 256, 0, stream>>>(hp, flng, flnb, fc1b16, fc1b, fc2b16, fc2b, out);
}

// Round 6
// 245.751 us; speedup vs baseline: 1.0619x; 1.0619x over previous
//
#include <hip/hip_runtime.h>

typedef __bf16 bf16x8 __attribute__((ext_vector_type(8)));
typedef float  f32x4  __attribute__((ext_vector_type(4)));
typedef unsigned short u16x8 __attribute__((ext_vector_type(8)));
typedef unsigned short u16x4 __attribute__((ext_vector_type(4)));

// Problem constants
constexpr int BB    = 16;
constexpr int TT    = 12;
constexpr int NN    = 307;
constexpr int TN    = TT * NN;        // 3684
constexpr int ROWSX = BB * TT * NN;   // 58944
constexpr int ROWSH = BB * NN;        // 4912
constexpr int SST1  = 3712;           // sag row stride (464 x b128 chunks)
constexpr int SSTR  = 3840;           // xnT row stride
constexpr int HPS   = ROWSH * 64;     // hp slab stride (314368 floats)
constexpr int KQ    = 928;            // pv K-split chunk (3712/4)
constexpr int WBS   = 152;            // score LDS stride: 76 dw = 12 mod 32 -> 2-way max
constexpr float SCALE = 0.125f;

__device__ __forceinline__ float wred_sum(float v) {
#pragma unroll
    for (int m = 32; m > 0; m >>= 1) v += __shfl_xor(v, m, 64);
    return v;
}

// ---------------------------------------------------------------------------
// prep_k: grid-specialized merge of fold (16 blk) + wconv (128 blk) + ln
// (14736 blk). All three depend only on kernel inputs; merging cuts 2
// dispatch gaps (~10us each) off the serial chain.
// ---------------------------------------------------------------------------
__global__ __launch_bounds__(256) void prep_k(const float* __restrict__ qw,
                                              const float* __restrict__ qb,
                                              const float* __restrict__ kw,
                                              const float* __restrict__ kb,
                                              const float* __restrict__ fc1w,
                                              const float* __restrict__ fc2w,
                                              const float* __restrict__ x,
                                              const float* __restrict__ g,
                                              const float* __restrict__ b,
                                              float* __restrict__ M,
                                              float* __restrict__ b2,
                                              float* __restrict__ vv,
                                              float* __restrict__ cc,
                                              __bf16* __restrict__ fc1b16,
                                              __bf16* __restrict__ fc2b16,
                                              __bf16* __restrict__ xnb,
                                              float* __restrict__ y32) {
    int bx = blockIdx.x, t = threadIdx.x;
    int w = t >> 6, lane = t & 63;
    if (bx < 16) {
        // ---- fold: dg = q.k = qt.x_ + c ----
        int e = bx * 4 + w, d = lane;
        float acc = 0.f;
        for (int dp = 0; dp < 64; ++dp) acc += qw[dp * 64 + e] * kw[dp * 64 + d];
        M[e * 64 + d] = acc;
        float vp = wred_sum(qw[d * 64 + e] * kb[d]);
        if (lane == 0) vv[e] = vp;
        if (e == 0) {
            float bv = 0.f;
            for (int dp = 0; dp < 64; ++dp) bv += qb[dp] * kw[dp * 64 + d];
            b2[d] = bv;
            float cp = wred_sum(qb[d] * kb[d]);
            if (d == 0) *cc = cp;
        }
    } else if (bx < 144) {
        // ---- wconv: fc1w/fc2w fp32 -> bf16 ----
        int i = (bx - 16) * 256 + t;
        if (i < 16384) fc1b16[i] = (__bf16)fc1w[i];
        else fc2b16[i - 16384] = (__bf16)fc2w[i - 16384];
    } else {
        // ---- ln: 1 row/wave ----
        int r = (bx - 144) * 4 + w;
        if (r >= ROWSX) return;
        float val = x[r * 64 + lane];
        float mu  = wred_sum(val) * (1.f / 64.f);
        float dv  = val - mu;
        float var = wred_sum(dv * dv) * (1.f / 64.f);
        float xv  = dv * rsqrtf(var + 1e-5f) * g[lane] + b[lane];
        xnb[(size_t)r * 64 + lane] = (__bf16)xv;
        int tt = (r / NN) % TT;
        if (tt == TT - 1) {
            int bbv = r / (NN * TT), n = r % NN;
            y32[(bbv * NN + n) * 64 + lane] = xv;
        }
    }
}

// ---------------------------------------------------------------------------
// tq_k: grid-specialized merge of transpose (928 blk) + qt (1228 blk).
// Both depend only on ln outputs; cuts 1 dispatch gap.
// ---------------------------------------------------------------------------
__global__ __launch_bounds__(256) void tq_k(const __bf16* __restrict__ xnb,
                                            __bf16* __restrict__ xnT,
                                            const float* __restrict__ y32,
                                            const float* __restrict__ M,
                                            const float* __restrict__ b2,
                                            const float* __restrict__ vv,
                                            const float* __restrict__ ccp,
                                            __bf16* __restrict__ qtb,
                                            float* __restrict__ cq) {
    __shared__ unsigned short tile[64][65];
    int bx = blockIdx.x, t = threadIdx.x;
    if (bx < 928) {
        // ---- transpose xnb[b,j,d] -> xnT[b,d,j] ----
        int bb = bx / 58, j0 = (bx % 58) * 64;
        const unsigned short* src = (const unsigned short*)xnb;
        unsigned short* dst = (unsigned short*)xnT;
#pragma unroll
        for (int i = 0; i < 16; ++i) {
            int f = t + 256 * i, jr = f >> 6, dc = f & 63;
            int j = j0 + jr;
            tile[jr][dc] = (j < TN) ? src[((size_t)bb * TN + j) * 64 + dc] : (unsigned short)0;
        }
        __syncthreads();
#pragma unroll
        for (int i = 0; i < 16; ++i) {
            int f = t + 256 * i, d = f >> 6, jj = f & 63;
            dst[((size_t)bb * 64 + d) * SSTR + j0 + jj] = tile[jj][d];
        }
    } else {
        // ---- qt[row] = y_ @ M + b2 (bf16); cq[row] = y_.v + cc ----
        int w = t >> 6, l = t & 63;
        int rr = (bx - 928) * 4 + w;
        if (rr >= ROWSH) return;
        float y = y32[rr * 64 + l];
        float acc = b2[l];
#pragma unroll
        for (int e = 0; e < 64; ++e) acc += __shfl(y, e, 64) * M[e * 64 + l];
        qtb[(size_t)rr * 64 + l] = (__bf16)acc;
        float cp = wred_sum(y * vv[l]);
        if (l == 0) cq[rr] = cp + *ccp;
    }
}

// ---------------------------------------------------------------------------
// Score GEMM via MFMA. Register-prefetch stg float4 + cq before MFMA; LDS
// stride 152 (2-way max on scatter); coalesced b128 stores.
// ---------------------------------------------------------------------------
__global__ __launch_bounds__(256, 4) void score_k(const __bf16* __restrict__ qtb,
                                                  const float* __restrict__ cq,
                                                  const __bf16* __restrict__ xnb,
                                                  const float* __restrict__ stg,
                                                  __bf16* __restrict__ sag) {
    __shared__ unsigned short wb[64 * WBS];   // 19.5 KB  [n(64)][j(128+pad)]
    int bb = blockIdx.z, n0 = blockIdx.y * 64, j0 = blockIdx.x * 128;
    int t = threadIdx.x;
    int w = t >> 6, lane = t & 63;
    int m16 = lane & 15, q4 = lane >> 4;

    // ---- prefetch stg tiles (8 x float4) + cq (4) into registers ----
    const float* stgb = stg + (size_t)bb * NN * TN;
    float4 sv[4][2];
    float cn[4];
#pragma unroll
    for (int nt = 0; nt < 4; ++nt) {
        int n = n0 + nt * 16 + m16;
        const float* srow = stgb + (size_t)min(n, NN - 1) * TN;
#pragma unroll
        for (int jj = 0; jj < 2; ++jj) {
            int jb = j0 + (w * 2 + jj) * 16 + q4 * 4;   // 4-aligned; TN is 4-aligned
            float4 s4 = {0.f, 0.f, 0.f, 0.f};
            if (jb < TN) s4 = *(const float4*)(srow + jb);
            sv[nt][jj] = s4;
        }
        cn[nt] = (n < NN) ? cq[bb * NN + n] : 0.f;
    }

    // ---- A fragments: xnb rows j (2 jt tiles per wave) ----
    bf16x8 a[2][2];
#pragma unroll
    for (int jj = 0; jj < 2; ++jj) {
        const bf16x8* ap = (const bf16x8*)(xnb + ((size_t)bb * TN + j0 + (w * 2 + jj) * 16 + m16) * 64);
        a[jj][0] = ap[q4];
        a[jj][1] = ap[q4 + 4];
    }

    // ---- MFMA: C[j_local][n_local], 2 jt x 4 nt tiles per wave ----
    f32x4 acc[2][4];
#pragma unroll
    for (int nt = 0; nt < 4; ++nt) {
        const bf16x8* bp = (const bf16x8*)(qtb + ((size_t)bb * NN + n0 + nt * 16 + m16) * 64);
        bf16x8 b0 = bp[q4], b1 = bp[q4 + 4];
#pragma unroll
        for (int jj = 0; jj < 2; ++jj) {
            f32x4 c = {0.f, 0.f, 0.f, 0.f};
            c = __builtin_amdgcn_mfma_f32_16x16x32_bf16(a[jj][0], b0, c, 0, 0, 0);
            c = __builtin_amdgcn_mfma_f32_16x16x32_bf16(a[jj][1], b1, c, 0, 0, 0);
            acc[jj][nt] = c;
        }
    }

    // ---- epilogue: sigmoid(dg)*stg*scale from registers only ----
#pragma unroll
    for (int nt = 0; nt < 4; ++nt) {
#pragma unroll
        for (int jj = 0; jj < 2; ++jj) {
            int jb = j0 + (w * 2 + jj) * 16 + q4 * 4;
            float svv[4] = {sv[nt][jj].x, sv[nt][jj].y, sv[nt][jj].z, sv[nt][jj].w};
            u16x4 hw;
#pragma unroll
            for (int r = 0; r < 4; ++r) {
                float dg = (acc[jj][nt][r] + cn[nt]) * SCALE;
                float s  = 1.f / (1.f + __expf(-dg));
                float wv = (jb + r < TN) ? s * svv[r] * SCALE : 0.f;
                __bf16 wb16 = (__bf16)wv;
                hw[r] = *(unsigned short*)&wb16;
            }
            *(u16x4*)&wb[(nt * 16 + m16) * WBS + (w * 2 + jj) * 16 + q4 * 4] = hw;
        }
    }
    __syncthreads();

    // ---- coalesced b128 stores ----
#pragma unroll
    for (int i = 0; i < 4; ++i) {
        int chunk = t + i * 256;          // 0..1023
        int row = chunk >> 4, c8 = (chunk & 15) * 8;
        int n = n0 + row;
        if (n < NN) {
            u16x8 v = *(const u16x8*)&wb[row * WBS + c8];
            *(u16x8*)((unsigned short*)sag + (size_t)(bb * NN + n) * SST1 + j0 + c8) = v;
        }
    }
}

// ---------------------------------------------------------------------------
// Softmax+topk, one wave per row, zero LDS (R4 config: the stats-only
// variant with inline exp in pv regressed -- exp VALU in pv's K-loop cost
// more than the 36.5MB write saved). Writes UNnormalized exp weights in
// place + per-row sum to rsum[]; pv divides in its epilogue.
// ---------------------------------------------------------------------------
__global__ __launch_bounds__(256) void smax_k(__bf16* __restrict__ sagB,
                                              const int* __restrict__ topk_p,
                                              float* __restrict__ rsum) {
    int t = threadIdx.x;
    int wid = t >> 6, lane = t & 63;
    int row = blockIdx.x * 4 + wid;
    if (row >= ROWSH) return;

    int topkv = *topk_p;
    bool selAll = (topkv <= 0);
    int kk = 0;
    if (!selAll) {
        kk = (topkv < 5) ? topkv * NN : topkv;
        if (kk > TN) kk = TN;
    }

    u16x8* src = (u16x8*)((unsigned short*)sagB + (size_t)row * SST1);
    u16x8 va[8];
#pragma unroll
    for (int ci = 0; ci < 8; ++ci) {
        int c = lane + (ci << 6);
        u16x8 v = {0, 0, 0, 0, 0, 0, 0, 0};
        if (c < 464) v = src[c];
        va[ci] = v;
    }
    // row max (values >= 0; bf16 bit order = value order; pads 0)
    int vmb = 0;
#pragma unroll
    for (int ci = 0; ci < 8; ++ci)
#pragma unroll
        for (int e = 0; e < 8; ++e) vmb = max(vmb, (int)va[ci][e]);
#pragma unroll
    for (int m = 32; m > 0; m >>= 1) vmb = max(vmb, __shfl_xor(vmb, m, 64));
    float vmax = __uint_as_float(((unsigned)vmb) << 16);

    // exact kk-th largest: smallest T with cnt(>T) < kk (ballot+popcount)
    unsigned thrb = 0;
    if (!selAll) {
        unsigned lo = 0, hi = (unsigned)vmb;
        while (lo < hi) {
            unsigned mid = (lo + hi) >> 1;
            int cnt = 0;
#pragma unroll
            for (int ci = 0; ci < 8; ++ci)
#pragma unroll
                for (int e = 0; e < 8; ++e)
                    cnt += (int)__popcll(__ballot((unsigned)va[ci][e] > mid));
            if (cnt < kk) hi = mid; else lo = mid + 1;
        }
        thrb = lo;
    }

    // exp over selected (store unnormalized exp as bf16)
    float local = 0.f;
#pragma unroll
    for (int ci = 0; ci < 8; ++ci) {
        int c = lane + (ci << 6);
        int nvv = (c < 460) ? 8 : ((c == 460) ? 4 : 0);
#pragma unroll
        for (int e = 0; e < 8; ++e) {
            unsigned u = va[ci][e];
            bool sel = selAll ? (e < nvv) : (u > thrb);
            float ev = sel ? __expf(__uint_as_float(u << 16) - vmax) : 0.f;
            local += ev;
            __bf16 eb = (__bf16)ev;
            va[ci][e] = *(unsigned short*)&eb;
        }
    }
    local = wred_sum(local);
    bool uni = !(local > 0.f);
    if (lane == 0) rsum[row] = uni ? (float)TN : local;

    if (uni) {
        __bf16 one = (__bf16)1.f, zero = (__bf16)0.f;
#pragma unroll
        for (int ci = 0; ci < 8; ++ci) {
            int c = lane + (ci << 6);
            if (c < 464) {
                int nvv = (c < 460) ? 8 : ((c == 460) ? 4 : 0);
                bf16x8 o;
#pragma unroll
                for (int e = 0; e < 8; ++e) o[e] = (e < nvv) ? one : zero;
                *(bf16x8*)&src[c] = o;
            }
        }
    } else {
#pragma unroll
        for (int ci = 0; ci < 8; ++ci) {
            int c = lane + (ci << 6);
            if (c < 464) src[c] = va[ci];
        }
    }
}

// ---------------------------------------------------------------------------
// PV GEMM, K-split 4 across blocks: hp[kq][b,n,d] = (sag[b,n,kq-chunk] @
// xnT[b,d,kq-chunk]^T) / rsum[b,n]  (+ y32 on kq==0). ffn_k sums the slabs.
// ---------------------------------------------------------------------------
__global__ __launch_bounds__(256) void pv_k(const __bf16* __restrict__ sagB,
                                            const __bf16* __restrict__ xnT,
                                            const float* __restrict__ y32,
                                            const float* __restrict__ rsum,
                                            float* __restrict__ hp) {
    int bb = blockIdx.z, kq = blockIdx.y, n0 = blockIdx.x * 16;
    int wid = threadIdx.x >> 6, lane = threadIdx.x & 63;
    int m16 = lane & 15, q4 = lane >> 4;

    int arow = min(n0 + m16, NN - 1);   // clamp: garbage rows masked at store
    const __bf16* ab  = sagB + (size_t)(bb * NN + arow) * SST1 + kq * KQ + q4 * 8;
    const __bf16* bbp = xnT + ((size_t)bb * 64 + wid * 16 + m16) * SSTR + kq * KQ + q4 * 8;

    f32x4 acc0 = {0.f, 0.f, 0.f, 0.f}, acc1 = {0.f, 0.f, 0.f, 0.f};
#pragma unroll 4
    for (int ks = 0; ks < 29; ++ks) {               // 29 * K32 = 928
        bf16x8 a = *(const bf16x8*)(ab + ks * 32);
        bf16x8 b = *(const bf16x8*)(bbp + ks * 32);
        if (ks & 1) acc1 = __builtin_amdgcn_mfma_f32_16x16x32_bf16(a, b, acc1, 0, 0, 0);
        else        acc0 = __builtin_amdgcn_mfma_f32_16x16x32_bf16(a, b, acc0, 0, 0, 0);
    }
    // C layout: row = q4*4+r (A-row = n), col = m16 (B-row = d within tile)
#pragma unroll
    for (int r = 0; r < 4; ++r) {
        int n = n0 + q4 * 4 + r;
        if (n < NN) {
            size_t o = (size_t)(bb * NN + n) * 64 + wid * 16 + m16;
            float inv = 1.f / rsum[bb * NN + n];
            float v = (acc0[r] + acc1[r]) * inv;
            if (kq == 0) v += y32[o];
            hp[(size_t)kq * HPS + o] = v;
        }
    }
}

// ---------------------------------------------------------------------------
// FFN via MFMA bf16: h = sum(hp[0..3]) -> LN -> @fc1^T+relu -> @fc2^T + h + b.
// hsum stashed in LDS during the LN pass (epilogue no longer re-reads the 4
// hp slabs from global).
// ---------------------------------------------------------------------------
__global__ __launch_bounds__(256) void ffn_k(const float* __restrict__ hp,
                                             const float* __restrict__ g,
                                             const float* __restrict__ bln,
                                             const __bf16* __restrict__ fc1b16,
                                             const float* __restrict__ fc1b,
                                             const __bf16* __restrict__ fc2b16,
                                             const float* __restrict__ fc2b,
                                             float* __restrict__ out) {
    __shared__ __bf16 zb[16 * 68];
    __shared__ __bf16 ab[16 * 264];
    __shared__ float hs[16][66];
    int t = threadIdx.x, r0 = blockIdx.x * 16;
    int wid = t >> 6, lane = t & 63;
    int m16 = lane & 15, q4 = lane >> 4;

#pragma unroll
    for (int q = 0; q < 4; ++q) {
        int rl = wid * 4 + q;
        size_t i = (size_t)(r0 + rl) * 64 + lane;
        float val = hp[i] + hp[HPS + i] + hp[2 * HPS + i] + hp[3 * HPS + i];
        hs[rl][lane] = val;
        float mu  = wred_sum(val) * (1.f / 64.f);
        float dv  = val - mu;
        float var = wred_sum(dv * dv) * (1.f / 64.f);
        zb[rl * 68 + lane] = (__bf16)(dv * rsqrtf(var + 1e-5f) * g[lane] + bln[lane]);
    }
    __syncthreads();

    bf16x8 a0 = *(const bf16x8*)&zb[m16 * 68 + q4 * 8];
    bf16x8 a1 = *(const bf16x8*)&zb[m16 * 68 + 32 + q4 * 8];
#pragma unroll
    for (int jt2 = 0; jt2 < 4; ++jt2) {
        int j0t = (wid * 4 + jt2) * 16;
        const __bf16* bp = fc1b16 + (size_t)(j0t + m16) * 64 + q4 * 8;
        f32x4 c = {0.f, 0.f, 0.f, 0.f};
        c = __builtin_amdgcn_mfma_f32_16x16x32_bf16(a0, *(const bf16x8*)bp, c, 0, 0, 0);
        c = __builtin_amdgcn_mfma_f32_16x16x32_bf16(a1, *(const bf16x8*)(bp + 32), c, 0, 0, 0);
        int j = j0t + m16;
        float bias = fc1b[j];
#pragma unroll
        for (int r = 0; r < 4; ++r)
            ab[(q4 * 4 + r) * 264 + j] = (__bf16)fmaxf(c[r] + bias, 0.f);
    }
    __syncthreads();

    f32x4 c2a = {0.f, 0.f, 0.f, 0.f}, c2b = {0.f, 0.f, 0.f, 0.f};
    const __bf16* b2p = fc2b16 + (size_t)(wid * 16 + m16) * 256 + q4 * 8;
#pragma unroll
    for (int k8 = 0; k8 < 8; k8 += 2) {
        bf16x8 aa0 = *(const bf16x8*)&ab[m16 * 264 + k8 * 32 + q4 * 8];
        bf16x8 aa1 = *(const bf16x8*)&ab[m16 * 264 + (k8 + 1) * 32 + q4 * 8];
        c2a = __builtin_amdgcn_mfma_f32_16x16x32_bf16(aa0, *(const bf16x8*)(b2p + k8 * 32), c2a, 0, 0, 0);
        c2b = __builtin_amdgcn_mfma_f32_16x16x32_bf16(aa1, *(const bf16x8*)(b2p + (k8 + 1) * 32), c2b, 0, 0, 0);
    }
    int d = wid * 16 + m16;
    float bias2 = fc2b[d];
#pragma unroll
    for (int r = 0; r < 4; ++r) {
        size_t row = (size_t)(r0 + q4 * 4 + r);
        size_t o = row * 64 + d;
        out[o] = hs[q4 * 4 + r][d] + c2a[r] + c2b[r] + bias2;
    }
}

extern "C" void kernel_launch(void* const* d_in, const int* in_sizes, int n_in,
                              void* d_out, int out_size, void* d_ws, size_t ws_size,
                              hipStream_t stream) {
    const float* x    = (const float*)d_in[0];
    const float* stg  = (const float*)d_in[1];
    const int*   topk = (const int*)d_in[2];
    const float* qw   = (const float*)d_in[3];
    const float* qb   = (const float*)d_in[4];
    const float* kw   = (const float*)d_in[5];
    const float* kb   = (const float*)d_in[6];
    const float* lng  = (const float*)d_in[7];
    const float* lnb  = (const float*)d_in[8];
    const float* flng = (const float*)d_in[9];
    const float* flnb = (const float*)d_in[10];
    const float* fc1w = (const float*)d_in[11];
    const float* fc1b = (const float*)d_in[12];
    const float* fc2w = (const float*)d_in[13];
    const float* fc2b = (const float*)d_in[14];
    float* out = (float*)d_out;

    float* ws = (float*)d_ws;
    __bf16* xnb = (__bf16*)ws;                 // ROWSX*64 bf16 = 1,886,208 f
    float* p1   = ws + 1886208;
    __bf16* xnT = (__bf16*)p1;                 // 16*64*3840 bf16 = 1,966,080 f
    float* p2   = p1 + 1966080;
    __bf16* qtb = (__bf16*)p2;                 // 4928*64 bf16 = 157,696 f
    float* y32  = p2 + 157696;                 // 314,368 f
    float* cq   = y32 + 314368;                // 4,928 f
    float* M    = cq + 4928;                   // 4,096
    float* b2   = M + 4096;                    // 64
    float* vv   = b2 + 64;                     // 64
    float* cc   = vv + 64;                     // 16
    __bf16* fc1b16 = (__bf16*)(cc + 16);       // 8,192 f
    __bf16* fc2b16 = (__bf16*)((float*)fc1b16 + 8192);  // 8,192 f
    __bf16* sag = (__bf16*)((float*)fc2b16 + 8192);     // ROWSH*3712 bf16 = 9,116,672 f
    float* hp   = (float*)sag + 9116672;       // 4*314,368 f (K-split partials)
    float* rsum = hp + 4 * HPS;                // 4,928 f

    prep_k<<<144 + (ROWSX + 3) / 4, 256, 0, stream>>>(qw, qb, kw, kb, fc1w, fc2w,
                                                      x, lng, lnb,
                                                      M, b2, vv, cc,
                                                      fc1b16, fc2b16, xnb, y32);
    tq_k<<<928 + (ROWSH + 3) / 4, 256, 0, stream>>>(xnb, xnT, y32, M, b2, vv, cc, qtb, cq);
    score_k<<<dim3((TN + 127) / 128, (NN + 63) / 64, BB), 256, 0, stream>>>(qtb, cq, xnb, stg, sag);
    smax_k<<<(ROWSH + 3) / 4, 256, 0, stream>>>(sag, topk, rsum);
    pv_k<<<dim3((NN + 15) / 16, 4, BB), 256, 0, stream>>>(sag, xnT, y32, rsum, hp);
    ffn_k<<<ROWSH / 16, 256, 0, stream>>>(hp, flng, flnb, fc1b16, fc1b, fc2b16, fc2b, out);
}

// Round 7
// 243.016 us; speedup vs baseline: 1.0739x; 1.0113x over previous
//
#include <hip/hip_runtime.h>

typedef __bf16 bf16x8 __attribute__((ext_vector_type(8)));
typedef float  f32x4  __attribute__((ext_vector_type(4)));
typedef unsigned short u16x8 __attribute__((ext_vector_type(8)));
typedef unsigned short u16x4 __attribute__((ext_vector_type(4)));

// Problem constants
constexpr int BB    = 16;
constexpr int TT    = 12;
constexpr int NN    = 307;
constexpr int TN    = TT * NN;        // 3684
constexpr int ROWSX = BB * TT * NN;   // 58944
constexpr int ROWSH = BB * NN;        // 4912
constexpr int SST1  = 3712;           // sag row stride (464 x b128 chunks)
constexpr int SSTR  = 3840;           // xnT row stride
constexpr int HPS   = ROWSH * 64;     // hp slab stride (314368 floats)
constexpr int KQ    = 928;            // pv K-split chunk (3712/4)
constexpr int WBS   = 152;            // score LDS stride: 76 dw = 12 mod 32 -> 2-way max
constexpr int SCORE_VB = 145 * BB;    // 29 j-blk x 5 n-blk x 16 = 2320
constexpr float SCALE = 0.125f;

__device__ __forceinline__ float wred_sum(float v) {
#pragma unroll
    for (int m = 32; m > 0; m >>= 1) v += __shfl_xor(v, m, 64);
    return v;
}

// ---------------------------------------------------------------------------
// prep_k: grid-specialized merge of fold (16 blk) + wconv (128 blk) + ln
// (14736 blk). All three depend only on kernel inputs.
// ---------------------------------------------------------------------------
__global__ __launch_bounds__(256) void prep_k(const float* __restrict__ qw,
                                              const float* __restrict__ qb,
                                              const float* __restrict__ kw,
                                              const float* __restrict__ kb,
                                              const float* __restrict__ fc1w,
                                              const float* __restrict__ fc2w,
                                              const float* __restrict__ x,
                                              const float* __restrict__ g,
                                              const float* __restrict__ b,
                                              float* __restrict__ M,
                                              float* __restrict__ b2,
                                              float* __restrict__ vv,
                                              float* __restrict__ cc,
                                              __bf16* __restrict__ fc1b16,
                                              __bf16* __restrict__ fc2b16,
                                              __bf16* __restrict__ xnb,
                                              float* __restrict__ y32) {
    int bx = blockIdx.x, t = threadIdx.x;
    int w = t >> 6, lane = t & 63;
    if (bx < 16) {
        // ---- fold: dg = q.k = qt.x_ + c ----
        int e = bx * 4 + w, d = lane;
        float acc = 0.f;
        for (int dp = 0; dp < 64; ++dp) acc += qw[dp * 64 + e] * kw[dp * 64 + d];
        M[e * 64 + d] = acc;
        float vp = wred_sum(qw[d * 64 + e] * kb[d]);
        if (lane == 0) vv[e] = vp;
        if (e == 0) {
            float bv = 0.f;
            for (int dp = 0; dp < 64; ++dp) bv += qb[dp] * kw[dp * 64 + d];
            b2[d] = bv;
            float cp = wred_sum(qb[d] * kb[d]);
            if (d == 0) *cc = cp;
        }
    } else if (bx < 144) {
        // ---- wconv: fc1w/fc2w fp32 -> bf16 ----
        int i = (bx - 16) * 256 + t;
        if (i < 16384) fc1b16[i] = (__bf16)fc1w[i];
        else fc2b16[i - 16384] = (__bf16)fc2w[i - 16384];
    } else {
        // ---- ln: 1 row/wave ----
        int r = (bx - 144) * 4 + w;
        if (r >= ROWSX) return;
        float val = x[r * 64 + lane];
        float mu  = wred_sum(val) * (1.f / 64.f);
        float dv  = val - mu;
        float var = wred_sum(dv * dv) * (1.f / 64.f);
        float xv  = dv * rsqrtf(var + 1e-5f) * g[lane] + b[lane];
        xnb[(size_t)r * 64 + lane] = (__bf16)xv;
        int tt = (r / NN) % TT;
        if (tt == TT - 1) {
            int bbv = r / (NN * TT), n = r % NN;
            y32[(bbv * NN + n) * 64 + lane] = xv;
        }
    }
}

// ---------------------------------------------------------------------------
// qt[row] = y_ @ M + b2 (bf16);  cq[row] = y_.v + cc  (standalone again;
// the transpose half of old tq_k now rides inside score's dispatch, off the
// critical path -- nothing before pv needs xnT).
// ---------------------------------------------------------------------------
__global__ __launch_bounds__(256) void qt_k(const float* __restrict__ y32,
                                            const float* __restrict__ M,
                                            const float* __restrict__ b2,
                                            const float* __restrict__ vv,
                                            const float* __restrict__ ccp,
                                            __bf16* __restrict__ qtb,
                                            float* __restrict__ cq) {
    int w = threadIdx.x >> 6, l = threadIdx.x & 63;
    int rr = blockIdx.x * 4 + w;
    if (rr >= ROWSH) return;
    float y = y32[rr * 64 + l];
    float acc = b2[l];
#pragma unroll
    for (int e = 0; e < 64; ++e) acc += __shfl(y, e, 64) * M[e * 64 + l];
    qtb[(size_t)rr * 64 + l] = (__bf16)acc;
    float cp = wred_sum(y * vv[l]);
    if (l == 0) cq[rr] = cp + *ccp;
}

// ---------------------------------------------------------------------------
// score_k + transpose rider. vb < 2320: score GEMM tile (64n x 128j).
// vb >= 2320: one 64j x 64d transpose tile of xnb -> xnT (reuses the score
// LDS buffer; overlaps score's latency-idle slots, removing t from the
// serial chain). Register-prefetch stg float4 + cq before MFMA; LDS stride
// 152 (2-way max); coalesced b128 stores.
// ---------------------------------------------------------------------------
__global__ __launch_bounds__(256, 4) void score_k(const __bf16* __restrict__ qtb,
                                                  const float* __restrict__ cq,
                                                  const __bf16* __restrict__ xnb,
                                                  const float* __restrict__ stg,
                                                  __bf16* __restrict__ sag,
                                                  __bf16* __restrict__ xnT) {
    __shared__ unsigned short wb[64 * WBS];   // 19.5 KB (score) / 8.3 KB (t)
    int vb = blockIdx.x;
    int t = threadIdx.x;

    if (vb >= SCORE_VB) {
        // ---- transpose rider: xnb[b,j,d] -> xnT[b,d,j] ----
        int u = vb - SCORE_VB;
        int bb = u / 58, j0 = (u % 58) * 64;
        unsigned short (*tile)[65] = (unsigned short(*)[65])wb;
        const unsigned short* src = (const unsigned short*)xnb;
        unsigned short* dst = (unsigned short*)xnT;
#pragma unroll
        for (int i = 0; i < 16; ++i) {
            int f = t + 256 * i, jr = f >> 6, dc = f & 63;
            int j = j0 + jr;
            tile[jr][dc] = (j < TN) ? src[((size_t)bb * TN + j) * 64 + dc] : (unsigned short)0;
        }
        __syncthreads();
#pragma unroll
        for (int i = 0; i < 16; ++i) {
            int f = t + 256 * i, d = f >> 6, jj = f & 63;
            dst[((size_t)bb * 64 + d) * SSTR + j0 + jj] = tile[jj][d];
        }
        return;
    }

    int jb = vb % 29, nb = (vb / 29) % 5, bb = vb / 145;
    int n0 = nb * 64, j0 = jb * 128;
    int w = t >> 6, lane = t & 63;
    int m16 = lane & 15, q4 = lane >> 4;

    // ---- prefetch stg tiles (8 x float4) + cq (4) into registers ----
    const float* stgb = stg + (size_t)bb * NN * TN;
    float4 sv[4][2];
    float cn[4];
#pragma unroll
    for (int nt = 0; nt < 4; ++nt) {
        int n = n0 + nt * 16 + m16;
        const float* srow = stgb + (size_t)min(n, NN - 1) * TN;
#pragma unroll
        for (int jj = 0; jj < 2; ++jj) {
            int jb2 = j0 + (w * 2 + jj) * 16 + q4 * 4;   // 4-aligned; TN is 4-aligned
            float4 s4 = {0.f, 0.f, 0.f, 0.f};
            if (jb2 < TN) s4 = *(const float4*)(srow + jb2);
            sv[nt][jj] = s4;
        }
        cn[nt] = (n < NN) ? cq[bb * NN + n] : 0.f;
    }

    // ---- A fragments: xnb rows j (2 jt tiles per wave) ----
    bf16x8 a[2][2];
#pragma unroll
    for (int jj = 0; jj < 2; ++jj) {
        const bf16x8* ap = (const bf16x8*)(xnb + ((size_t)bb * TN + j0 + (w * 2 + jj) * 16 + m16) * 64);
        a[jj][0] = ap[q4];
        a[jj][1] = ap[q4 + 4];
    }

    // ---- MFMA: C[j_local][n_local], 2 jt x 4 nt tiles per wave ----
    f32x4 acc[2][4];
#pragma unroll
    for (int nt = 0; nt < 4; ++nt) {
        const bf16x8* bp = (const bf16x8*)(qtb + ((size_t)bb * NN + n0 + nt * 16 + m16) * 64);
        bf16x8 b0 = bp[q4], b1 = bp[q4 + 4];
#pragma unroll
        for (int jj = 0; jj < 2; ++jj) {
            f32x4 c = {0.f, 0.f, 0.f, 0.f};
            c = __builtin_amdgcn_mfma_f32_16x16x32_bf16(a[jj][0], b0, c, 0, 0, 0);
            c = __builtin_amdgcn_mfma_f32_16x16x32_bf16(a[jj][1], b1, c, 0, 0, 0);
            acc[jj][nt] = c;
        }
    }

    // ---- epilogue: sigmoid(dg)*stg*scale from registers only ----
#pragma unroll
    for (int nt = 0; nt < 4; ++nt) {
#pragma unroll
        for (int jj = 0; jj < 2; ++jj) {
            int jb2 = j0 + (w * 2 + jj) * 16 + q4 * 4;
            float svv[4] = {sv[nt][jj].x, sv[nt][jj].y, sv[nt][jj].z, sv[nt][jj].w};
            u16x4 hw;
#pragma unroll
            for (int r = 0; r < 4; ++r) {
                float dg = (acc[jj][nt][r] + cn[nt]) * SCALE;
                float s  = 1.f / (1.f + __expf(-dg));
                float wv = (jb2 + r < TN) ? s * svv[r] * SCALE : 0.f;
                __bf16 wb16 = (__bf16)wv;
                hw[r] = *(unsigned short*)&wb16;
            }
            *(u16x4*)&wb[(nt * 16 + m16) * WBS + (w * 2 + jj) * 16 + q4 * 4] = hw;
        }
    }
    __syncthreads();

    // ---- coalesced b128 stores ----
#pragma unroll
    for (int i = 0; i < 4; ++i) {
        int chunk = t + i * 256;          // 0..1023
        int row = chunk >> 4, c8 = (chunk & 15) * 8;
        int n = n0 + row;
        if (n < NN) {
            u16x8 v = *(const u16x8*)&wb[row * WBS + c8];
            *(u16x8*)((unsigned short*)sag + (size_t)(bb * NN + n) * SST1 + j0 + c8) = v;
        }
    }
}

// ---------------------------------------------------------------------------
// Softmax+topk, one wave per row, zero LDS. Writes UNnormalized exp weights
// in place + per-row sum to rsum[]; pv divides in its epilogue.
// ---------------------------------------------------------------------------
__global__ __launch_bounds__(256) void smax_k(__bf16* __restrict__ sagB,
                                              const int* __restrict__ topk_p,
                                              float* __restrict__ rsum) {
    int t = threadIdx.x;
    int wid = t >> 6, lane = t & 63;
    int row = blockIdx.x * 4 + wid;
    if (row >= ROWSH) return;

    int topkv = *topk_p;
    bool selAll = (topkv <= 0);
    int kk = 0;
    if (!selAll) {
        kk = (topkv < 5) ? topkv * NN : topkv;
        if (kk > TN) kk = TN;
    }

    u16x8* src = (u16x8*)((unsigned short*)sagB + (size_t)row * SST1);
    u16x8 va[8];
#pragma unroll
    for (int ci = 0; ci < 8; ++ci) {
        int c = lane + (ci << 6);
        u16x8 v = {0, 0, 0, 0, 0, 0, 0, 0};
        if (c < 464) v = src[c];
        va[ci] = v;
    }
    // row max (values >= 0; bf16 bit order = value order; pads 0)
    int vmb = 0;
#pragma unroll
    for (int ci = 0; ci < 8; ++ci)
#pragma unroll
        for (int e = 0; e < 8; ++e) vmb = max(vmb, (int)va[ci][e]);
#pragma unroll
    for (int m = 32; m > 0; m >>= 1) vmb = max(vmb, __shfl_xor(vmb, m, 64));
    float vmax = __uint_as_float(((unsigned)vmb) << 16);

    // exact kk-th largest: smallest T with cnt(>T) < kk (ballot+popcount)
    unsigned thrb = 0;
    if (!selAll) {
        unsigned lo = 0, hi = (unsigned)vmb;
        while (lo < hi) {
            unsigned mid = (lo + hi) >> 1;
            int cnt = 0;
#pragma unroll
            for (int ci = 0; ci < 8; ++ci)
#pragma unroll
                for (int e = 0; e < 8; ++e)
                    cnt += (int)__popcll(__ballot((unsigned)va[ci][e] > mid));
            if (cnt < kk) hi = mid; else lo = mid + 1;
        }
        thrb = lo;
    }

    // exp over selected (store unnormalized exp as bf16)
    float local = 0.f;
#pragma unroll
    for (int ci = 0; ci < 8; ++ci) {
        int c = lane + (ci << 6);
        int nvv = (c < 460) ? 8 : ((c == 460) ? 4 : 0);
#pragma unroll
        for (int e = 0; e < 8; ++e) {
            unsigned u = va[ci][e];
            bool sel = selAll ? (e < nvv) : (u > thrb);
            float ev = sel ? __expf(__uint_as_float(u << 16) - vmax) : 0.f;
            local += ev;
            __bf16 eb = (__bf16)ev;
            va[ci][e] = *(unsigned short*)&eb;
        }
    }
    local = wred_sum(local);
    bool uni = !(local > 0.f);
    if (lane == 0) rsum[row] = uni ? (float)TN : local;

    if (uni) {
        __bf16 one = (__bf16)1.f, zero = (__bf16)0.f;
#pragma unroll
        for (int ci = 0; ci < 8; ++ci) {
            int c = lane + (ci << 6);
            if (c < 464) {
                int nvv = (c < 460) ? 8 : ((c == 460) ? 4 : 0);
                bf16x8 o;
#pragma unroll
                for (int e = 0; e < 8; ++e) o[e] = (e < nvv) ? one : zero;
                *(bf16x8*)&src[c] = o;
            }
        }
    } else {
#pragma unroll
        for (int ci = 0; ci < 8; ++ci) {
            int c = lane + (ci << 6);
            if (c < 464) src[c] = va[ci];
        }
    }
}

// ---------------------------------------------------------------------------
// PV GEMM, K-split 4 across blocks, XCD-swizzled: all 20 n-blocks sharing
// one (bb,kq) xnT panel (119 KB) land on ONE XCD's L2 (panel fetched once,
// not once per XCD: ~50 MB of HBM refetch removed). 1280 = 8 x 160 exactly,
// so l=(p&7)*160+p/8 is bijective. hp[kq] summed by ffn_k.
// ---------------------------------------------------------------------------
__global__ __launch_bounds__(256) void pv_k(const __bf16* __restrict__ sagB,
                                            const __bf16* __restrict__ xnT,
                                            const float* __restrict__ y32,
                                            const float* __restrict__ rsum,
                                            float* __restrict__ hp) {
    int p = blockIdx.x + 20 * (blockIdx.y + 4 * blockIdx.z);   // 0..1279
    int l = (p & 7) * 160 + (p >> 3);
    int n0 = (l % 20) * 16;
    int kq = (l / 20) & 3;
    int bb = l / 80;
    int wid = threadIdx.x >> 6, lane = threadIdx.x & 63;
    int m16 = lane & 15, q4 = lane >> 4;

    int arow = min(n0 + m16, NN - 1);   // clamp: garbage rows masked at store
    const __bf16* ab  = sagB + (size_t)(bb * NN + arow) * SST1 + kq * KQ + q4 * 8;
    const __bf16* bbp = xnT + ((size_t)bb * 64 + wid * 16 + m16) * SSTR + kq * KQ + q4 * 8;

    f32x4 acc0 = {0.f, 0.f, 0.f, 0.f}, acc1 = {0.f, 0.f, 0.f, 0.f};
#pragma unroll 4
    for (int ks = 0; ks < 29; ++ks) {               // 29 * K32 = 928
        bf16x8 a = *(const bf16x8*)(ab + ks * 32);
        bf16x8 b = *(const bf16x8*)(bbp + ks * 32);
        if (ks & 1) acc1 = __builtin_amdgcn_mfma_f32_16x16x32_bf16(a, b, acc1, 0, 0, 0);
        else        acc0 = __builtin_amdgcn_mfma_f32_16x16x32_bf16(a, b, acc0, 0, 0, 0);
    }
    // C layout: row = q4*4+r (A-row = n), col = m16 (B-row = d within tile)
#pragma unroll
    for (int r = 0; r < 4; ++r) {
        int n = n0 + q4 * 4 + r;
        if (n < NN) {
            size_t o = (size_t)(bb * NN + n) * 64 + wid * 16 + m16;
            float inv = 1.f / rsum[bb * NN + n];
            float v = (acc0[r] + acc1[r]) * inv;
            if (kq == 0) v += y32[o];
            hp[(size_t)kq * HPS + o] = v;
        }
    }
}

// ---------------------------------------------------------------------------
// FFN via MFMA bf16: h = sum(hp[0..3]) -> LN -> @fc1^T+relu -> @fc2^T + h + b.
// hsum stashed in LDS during the LN pass.
// ---------------------------------------------------------------------------
__global__ __launch_bounds__(256) void ffn_k(const float* __restrict__ hp,
                                             const float* __restrict__ g,
                                             const float* __restrict__ bln,
                                             const __bf16* __restrict__ fc1b16,
                                             const float* __restrict__ fc1b,
                                             const __bf16* __restrict__ fc2b16,
                                             const float* __restrict__ fc2b,
                                             float* __restrict__ out) {
    __shared__ __bf16 zb[16 * 68];
    __shared__ __bf16 ab[16 * 264];
    __shared__ float hs[16][66];
    int t = threadIdx.x, r0 = blockIdx.x * 16;
    int wid = t >> 6, lane = t & 63;
    int m16 = lane & 15, q4 = lane >> 4;

#pragma unroll
    for (int q = 0; q < 4; ++q) {
        int rl = wid * 4 + q;
        size_t i = (size_t)(r0 + rl) * 64 + lane;
        float val = hp[i] + hp[HPS + i] + hp[2 * HPS + i] + hp[3 * HPS + i];
        hs[rl][lane] = val;
        float mu  = wred_sum(val) * (1.f / 64.f);
        float dv  = val - mu;
        float var = wred_sum(dv * dv) * (1.f / 64.f);
        zb[rl * 68 + lane] = (__bf16)(dv * rsqrtf(var + 1e-5f) * g[lane] + bln[lane]);
    }
    __syncthreads();

    bf16x8 a0 = *(const bf16x8*)&zb[m16 * 68 + q4 * 8];
    bf16x8 a1 = *(const bf16x8*)&zb[m16 * 68 + 32 + q4 * 8];
#pragma unroll
    for (int jt2 = 0; jt2 < 4; ++jt2) {
        int j0t = (wid * 4 + jt2) * 16;
        const __bf16* bp = fc1b16 + (size_t)(j0t + m16) * 64 + q4 * 8;
        f32x4 c = {0.f, 0.f, 0.f, 0.f};
        c = __builtin_amdgcn_mfma_f32_16x16x32_bf16(a0, *(const bf16x8*)bp, c, 0, 0, 0);
        c = __builtin_amdgcn_mfma_f32_16x16x32_bf16(a1, *(const bf16x8*)(bp + 32), c, 0, 0, 0);
        int j = j0t + m16;
        float bias = fc1b[j];
#pragma unroll
        for (int r = 0; r < 4; ++r)
            ab[(q4 * 4 + r) * 264 + j] = (__bf16)fmaxf(c[r] + bias, 0.f);
    }
    __syncthreads();

    f32x4 c2a = {0.f, 0.f, 0.f, 0.f}, c2b = {0.f, 0.f, 0.f, 0.f};
    const __bf16* b2p = fc2b16 + (size_t)(wid * 16 + m16) * 256 + q4 * 8;
#pragma unroll
    for (int k8 = 0; k8 < 8; k8 += 2) {
        bf16x8 aa0 = *(const bf16x8*)&ab[m16 * 264 + k8 * 32 + q4 * 8];
        bf16x8 aa1 = *(const bf16x8*)&ab[m16 * 264 + (k8 + 1) * 32 + q4 * 8];
        c2a = __builtin_amdgcn_mfma_f32_16x16x32_bf16(aa0, *(const bf16x8*)(b2p + k8 * 32), c2a, 0, 0, 0);
        c2b = __builtin_amdgcn_mfma_f32_16x16x32_bf16(aa1, *(const bf16x8*)(b2p + (k8 + 1) * 32), c2b, 0, 0, 0);
    }
    int d = wid * 16 + m16;
    float bias2 = fc2b[d];
#pragma unroll
    for (int r = 0; r < 4; ++r) {
        size_t row = (size_t)(r0 + q4 * 4 + r);
        size_t o = row * 64 + d;
        out[o] = hs[q4 * 4 + r][d] + c2a[r] + c2b[r] + bias2;
    }
}

extern "C" void kernel_launch(void* const* d_in, const int* in_sizes, int n_in,
                              void* d_out, int out_size, void* d_ws, size_t ws_size,
                              hipStream_t stream) {
    const float* x    = (const float*)d_in[0];
    const float* stg  = (const float*)d_in[1];
    const int*   topk = (const int*)d_in[2];
    const float* qw   = (const float*)d_in[3];
    const float* qb   = (const float*)d_in[4];
    const float* kw   = (const float*)d_in[5];
    const float* kb   = (const float*)d_in[6];
    const float* lng  = (const float*)d_in[7];
    const float* lnb  = (const float*)d_in[8];
    const float* flng = (const float*)d_in[9];
    const float* flnb = (const float*)d_in[10];
    const float* fc1w = (const float*)d_in[11];
    const float* fc1b = (const float*)d_in[12];
    const float* fc2w = (const float*)d_in[13];
    const float* fc2b = (const float*)d_in[14];
    float* out = (float*)d_out;

    float* ws = (float*)d_ws;
    __bf16* xnb = (__bf16*)ws;                 // ROWSX*64 bf16 = 1,886,208 f
    float* p1   = ws + 1886208;
    __bf16* xnT = (__bf16*)p1;                 // 16*64*3840 bf16 = 1,966,080 f
    float* p2   = p1 + 1966080;
    __bf16* qtb = (__bf16*)p2;                 // 4928*64 bf16 = 157,696 f
    float* y32  = p2 + 157696;                 // 314,368 f
    float* cq   = y32 + 314368;                // 4,928 f
    float* M    = cq + 4928;                   // 4,096
    float* b2   = M + 4096;                    // 64
    float* vv   = b2 + 64;                     // 64
    float* cc   = vv + 64;                     // 16
    __bf16* fc1b16 = (__bf16*)(cc + 16);       // 8,192 f
    __bf16* fc2b16 = (__bf16*)((float*)fc1b16 + 8192);  // 8,192 f
    __bf16* sag = (__bf16*)((float*)fc2b16 + 8192);     // ROWSH*3712 bf16 = 9,116,672 f
    float* hp   = (float*)sag + 9116672;       // 4*314,368 f (K-split partials)
    float* rsum = hp + 4 * HPS;                // 4,928 f

    prep_k<<<144 + (ROWSX + 3) / 4, 256, 0, stream>>>(qw, qb, kw, kb, fc1w, fc2w,
                                                      x, lng, lnb,
                                                      M, b2, vv, cc,
                                                      fc1b16, fc2b16, xnb, y32);
    qt_k<<<(ROWSH + 3) / 4, 256, 0, stream>>>(y32, M, b2, vv, cc, qtb, cq);
    score_k<<<SCORE_VB + 58 * BB, 256, 0, stream>>>(qtb, cq, xnb, stg, sag, xnT);
    smax_k<<<(ROWSH + 3) / 4, 256, 0, stream>>>(sag, topk, rsum);
    pv_k<<<dim3((NN + 15) / 16, 4, BB), 256, 0, stream>>>(sag, xnT, y32, rsum, hp);
    ffn_k<<<ROWSH / 16, 256, 0, stream>>>(hp, flng, flnb, fc1b16, fc1b, fc2b16, fc2b, out);
}